// Round 2
// baseline (132738.831 us; speedup 1.0000x reference)
//
#include <hip/hip_runtime.h>
#include <hip/hip_bf16.h>

// Adaptive binary arithmetic encoder, bit-exact port of the JAX reference.
// Phase 1 (parallel): bits/contexts -> per-position adaptive frequency f (12b)
// Phase 2 (sequential, 1 thread): arithmetic coder with batched renorm
// Phase 3 (parallel): bytes -> int32 outputs (harness reads d_out as int32)
//
// ws layout (bytes):
//   0       : hdr[2]  (nbits, nwords)
//   4096    : outw    (262144 B bitstream buffer = 2^21 bits)
//   266240  : histG   (256 blocks * 512 keys * u32)
//   790528  : offsG   (same shape, exclusive scan over blocks)
//   1314816 : keys    (u16 * 2^20)  key = state<<1 | bit
//   3411968 : fb      (u16 * 2^20)  f | bit<<15

#define N_TOT (1 << 20)
#define BLK_ELEMS 4096
#define N_BLKS (N_TOT / BLK_ELEMS)   // 256

__global__ void k_keys(const float* __restrict__ sym, unsigned short* __restrict__ keys) {
    int t = blockIdx.x * blockDim.x + threadIdx.x;
    if (t >= N_TOT) return;
    unsigned s = 0;
#pragma unroll
    for (int i = 1; i <= 8; ++i) {
        unsigned b = (t >= i) ? (sym[t - i] > 0.0f ? 1u : 0u) : 0u;
        s |= b << (i - 1);
    }
    unsigned bit = sym[t] > 0.0f ? 1u : 0u;
    keys[t] = (unsigned short)((s << 1) | bit);
}

__global__ void k_hist(const unsigned short* __restrict__ keys, unsigned* __restrict__ histG) {
    __shared__ unsigned h[512];
    for (int i = threadIdx.x; i < 512; i += blockDim.x) h[i] = 0;
    __syncthreads();
    int base = blockIdx.x * BLK_ELEMS;
    for (int i = threadIdx.x; i < BLK_ELEMS; i += blockDim.x)
        atomicAdd(&h[keys[base + i]], 1u);
    __syncthreads();
    for (int i = threadIdx.x; i < 512; i += blockDim.x)
        histG[blockIdx.x * 512 + i] = h[i];
}

__global__ void k_scan(const unsigned* __restrict__ histG, unsigned* __restrict__ offsG) {
    int k = blockIdx.x * blockDim.x + threadIdx.x;
    if (k >= 512) return;
    unsigned run = 0;
    for (int b = 0; b < N_BLKS; ++b) {
        offsG[b * 512 + k] = run;
        run += histG[b * 512 + k];
    }
}

__global__ __launch_bounds__(64) void k_freq(const unsigned short* __restrict__ keys,
                                             const unsigned* __restrict__ offsG,
                                             unsigned short* __restrict__ fb) {
    __shared__ unsigned cnt[512];
    int lane = threadIdx.x;
    for (int i = lane; i < 512; i += 64) cnt[i] = offsG[blockIdx.x * 512 + i];
    __syncthreads();
    int base = blockIdx.x * BLK_ELEMS;
    unsigned long long ltm = (1ull << lane) - 1ull;
    for (int c = 0; c < BLK_ELEMS / 64; ++c) {
        int t = base + c * 64 + lane;
        unsigned key = keys[t];
        unsigned bit = key & 1u;
        unsigned state = key >> 1;
        // 64-lane equality mask on the 8-bit state via ballots
        unsigned long long eq = ~0ull;
#pragma unroll
        for (int b = 0; b < 8; ++b) {
            unsigned long long mb = __ballot((state >> b) & 1u);
            eq &= ((state >> b) & 1u) ? mb : ~mb;
        }
        unsigned long long bb = __ballot(bit);
        unsigned long long same = eq & (bit ? bb : ~bb);   // same (state,bit)
        unsigned long long sib  = eq & (bit ? ~bb : bb);   // same state, other bit
        unsigned base_same = cnt[key];
        unsigned base_sib  = cnt[key ^ 1u];
        __syncthreads();   // all reads done before the group-writer updates
        unsigned c_same = base_same + (unsigned)__popcll(same & ltm);
        unsigned c_sib  = base_sib  + (unsigned)__popcll(sib & ltm);
        unsigned long long a0 = 1ull + (unsigned long long)(bit ? c_sib : c_same); // count of zeros (+prior)
        unsigned long long a1 = 1ull + (unsigned long long)(bit ? c_same : c_sib); // count of ones  (+prior)
        double p0 = (double)a0 / (double)(a0 + a1);
        double fd = rint(p0 * 4094.0) + 1.0;
        fd = fd < 1.0 ? 1.0 : (fd > 4095.0 ? 4095.0 : fd);
        unsigned f = (unsigned)fd;
        fb[t] = (unsigned short)(f | (bit << 15));
        // highest lane of each same-key group commits the group's increment
        int hi = 63 - __builtin_clzll(same);
        if (lane == hi) cnt[key] = base_same + (unsigned)__popcll(same);
        __syncthreads();
    }
}

__global__ void k_encode(const unsigned short* __restrict__ fb,
                         unsigned* __restrict__ outw, unsigned* __restrict__ hdr) {
    if (threadIdx.x != 0 || blockIdx.x != 0) return;
    unsigned low = 0u, high = 0xFFFFFFFFu;
    unsigned pending = 0;
    unsigned acc = 0; int nacc = 0; int wp = 0; unsigned nb = 0;

    auto EMIT = [&](unsigned b) {
        acc = (acc << 1) | b;
        if (++nacc == 32) { outw[wp++] = __builtin_bswap32(acc); nacc = 0; }
        ++nb;
    };

    for (int c = 0; c < N_TOT / 64; ++c) {
        union { uint4 v[8]; unsigned short u[64]; } L;
        const uint4* p = (const uint4*)(fb + c * 64);
#pragma unroll
        for (int i = 0; i < 8; ++i) L.v[i] = p[i];
#pragma unroll
        for (int j = 0; j < 64; ++j) {
            unsigned val = L.u[j];
            unsigned f = val & 0xFFFu;
            unsigned bit = val >> 15;
            unsigned long long rng = (unsigned long long)(high - low) + 1ull;
            unsigned split = low + (unsigned)((rng * (unsigned long long)f) >> 12);
            if (bit) low = split; else high = split - 1u;

            // batched common-leading-bit emission
            unsigned x = low ^ high;
            int k = x ? __builtin_clz(x) : 32;
            if (k > 0) {
                unsigned b0 = low >> 31;
                EMIT(b0);
                while (pending) { EMIT(1u - b0); --pending; }
                for (int i = 1; i < k; ++i) EMIT((low >> (31 - i)) & 1u);
                unsigned long long ones = (k == 32) ? 0xFFFFFFFFull : ((1ull << k) - 1ull);
                low  = (unsigned)((unsigned long long)low  << k);
                high = (unsigned)((((unsigned long long)high << k) | ones));
            }
            // batched E3 (straddle) steps
            unsigned t1 = low << 1;   // low  < HALF here
            unsigned t2 = high << 1;  // high >= HALF here
            unsigned nt1 = ~t1;
            int a = nt1 ? __builtin_clz(nt1) : 32;
            int b2 = t2 ? __builtin_clz(t2) : 32;
            int m = a < b2 ? a : b2;
            if (m > 0) {
                pending += (unsigned)m;
                unsigned long long pw = 1ull << m;
                unsigned long long sub = (pw - 1ull) << 31;   // (2^m-1)*HALF
                low  = (unsigned)(((unsigned long long)low  << m) - sub);
                high = (unsigned)((((unsigned long long)high << m) - sub) + (pw - 1ull));
            }
        }
    }
    // flush
    pending += 1u;
    unsigned fbit = (low >= 0x40000000u) ? 1u : 0u;
    EMIT(fbit);
    while (pending) { EMIT(1u - fbit); --pending; }
    if (nacc > 0) { outw[wp++] = __builtin_bswap32(acc << (32 - nacc)); }
    hdr[0] = nb;
    hdr[1] = (unsigned)wp;
}

__global__ void k_out(const unsigned char* __restrict__ bytes,
                      const unsigned* __restrict__ hdr, int* __restrict__ out) {
    int i = blockIdx.x * blockDim.x + threadIdx.x;
    if (i > 262144) return;
    if (i == 262144) { out[i] = (int)hdr[0]; return; }
    unsigned nbytes = hdr[1] * 4u;
    out[i] = ((unsigned)i < nbytes) ? (int)bytes[i] : 0;
}

extern "C" void kernel_launch(void* const* d_in, const int* in_sizes, int n_in,
                              void* d_out, int out_size, void* d_ws, size_t ws_size,
                              hipStream_t stream) {
    (void)in_sizes; (void)n_in; (void)out_size; (void)ws_size;
    const float* sym = (const float*)d_in[0];
    int* out = (int*)d_out;
    char* ws = (char*)d_ws;
    unsigned*       hdr   = (unsigned*)(ws);
    unsigned*       outw  = (unsigned*)(ws + 4096);
    unsigned*       histG = (unsigned*)(ws + 266240);
    unsigned*       offsG = (unsigned*)(ws + 790528);
    unsigned short* keys  = (unsigned short*)(ws + 1314816);
    unsigned short* fb    = (unsigned short*)(ws + 3411968);

    k_keys<<<N_TOT / 256, 256, 0, stream>>>(sym, keys);
    k_hist<<<N_BLKS, 256, 0, stream>>>(keys, histG);
    k_scan<<<1, 512, 0, stream>>>(histG, offsG);
    k_freq<<<N_BLKS, 64, 0, stream>>>(keys, offsG, fb);
    k_encode<<<1, 64, 0, stream>>>(fb, outw, hdr);
    k_out<<<1025, 256, 0, stream>>>((const unsigned char*)outw, hdr, out);
}

// Round 6
// 121387.646 us; speedup vs baseline: 1.0935x; 1.0935x over previous
//
#include <hip/hip_runtime.h>
#include <hip/hip_bf16.h>

// Adaptive binary arithmetic encoder, bit-exact port of the JAX reference.
// Phase 1 (parallel): bits/contexts -> per-position adaptive frequency f (12b)
// Phase 2 (sequential, 1 lane): arithmetic coder; batched renorm + batched
//         bit-append (no per-bit loop), scalarized via readfirstlane
// Phase 3 (parallel): bytes -> int32 outputs (harness reads d_out as int32)
//
// ws layout (bytes):
//   0       : hdr[2]  (nbits, nwords)
//   4096    : outw    (262144 B bitstream buffer = 2^21 bits)
//   266240  : histG   (256 blocks * 512 keys * u32)
//   790528  : offsG   (same shape, exclusive scan over blocks)
//   1314816 : keys    (u16 * 2^20)  key = state<<1 | bit
//   3411968 : fb      (u16 * 2^20)  f | bit<<15

#define N_TOT (1 << 20)
#define BLK_ELEMS 4096
#define N_BLKS (N_TOT / BLK_ELEMS)   // 256

__global__ void k_keys(const float* __restrict__ sym, unsigned short* __restrict__ keys) {
    int t = blockIdx.x * blockDim.x + threadIdx.x;
    if (t >= N_TOT) return;
    unsigned s = 0;
#pragma unroll
    for (int i = 1; i <= 8; ++i) {
        unsigned b = (t >= i) ? (sym[t - i] > 0.0f ? 1u : 0u) : 0u;
        s |= b << (i - 1);
    }
    unsigned bit = sym[t] > 0.0f ? 1u : 0u;
    keys[t] = (unsigned short)((s << 1) | bit);
}

__global__ void k_hist(const unsigned short* __restrict__ keys, unsigned* __restrict__ histG) {
    __shared__ unsigned h[512];
    for (int i = threadIdx.x; i < 512; i += blockDim.x) h[i] = 0;
    __syncthreads();
    int base = blockIdx.x * BLK_ELEMS;
    for (int i = threadIdx.x; i < BLK_ELEMS; i += blockDim.x)
        atomicAdd(&h[keys[base + i]], 1u);
    __syncthreads();
    for (int i = threadIdx.x; i < 512; i += blockDim.x)
        histG[blockIdx.x * 512 + i] = h[i];
}

__global__ void k_scan(const unsigned* __restrict__ histG, unsigned* __restrict__ offsG) {
    int k = blockIdx.x * blockDim.x + threadIdx.x;
    if (k >= 512) return;
    unsigned run = 0;
    for (int b = 0; b < N_BLKS; ++b) {
        offsG[b * 512 + k] = run;
        run += histG[b * 512 + k];
    }
}

__global__ __launch_bounds__(64) void k_freq(const unsigned short* __restrict__ keys,
                                             const unsigned* __restrict__ offsG,
                                             unsigned short* __restrict__ fb) {
    __shared__ unsigned cnt[512];
    int lane = threadIdx.x;
    for (int i = lane; i < 512; i += 64) cnt[i] = offsG[blockIdx.x * 512 + i];
    __syncthreads();
    int base = blockIdx.x * BLK_ELEMS;
    unsigned long long ltm = (1ull << lane) - 1ull;
    for (int c = 0; c < BLK_ELEMS / 64; ++c) {
        int t = base + c * 64 + lane;
        unsigned key = keys[t];
        unsigned bit = key & 1u;
        unsigned state = key >> 1;
        unsigned long long eq = ~0ull;
#pragma unroll
        for (int b = 0; b < 8; ++b) {
            unsigned long long mb = __ballot((state >> b) & 1u);
            eq &= ((state >> b) & 1u) ? mb : ~mb;
        }
        unsigned long long bb = __ballot(bit);
        unsigned long long same = eq & (bit ? bb : ~bb);
        unsigned long long sib  = eq & (bit ? ~bb : bb);
        unsigned base_same = cnt[key];
        unsigned base_sib  = cnt[key ^ 1u];
        __syncthreads();
        unsigned c_same = base_same + (unsigned)__popcll(same & ltm);
        unsigned c_sib  = base_sib  + (unsigned)__popcll(sib & ltm);
        unsigned long long a0 = 1ull + (unsigned long long)(bit ? c_sib : c_same);
        unsigned long long a1 = 1ull + (unsigned long long)(bit ? c_same : c_sib);
        double p0 = (double)a0 / (double)(a0 + a1);
        double fd = rint(p0 * 4094.0) + 1.0;
        fd = fd < 1.0 ? 1.0 : (fd > 4095.0 ? 4095.0 : fd);
        unsigned f = (unsigned)fd;
        fb[t] = (unsigned short)(f | (bit << 15));
        int hi = 63 - __builtin_clzll(same);
        if (lane == hi) cnt[key] = base_same + (unsigned)__popcll(same);
        __syncthreads();
    }
}

__global__ __launch_bounds__(64) void k_encode(const unsigned short* __restrict__ fb,
                                               unsigned* __restrict__ outw,
                                               unsigned* __restrict__ hdr) {
    if (threadIdx.x != 0 || blockIdx.x != 0) return;
    unsigned low = 0u, high = 0xFFFFFFFFu;
    unsigned pending = 0, nb = 0, nacc = 0, wp = 0;
    unsigned long long acc = 0;

    auto EMIT1 = [&](unsigned b) {
        acc = (acc << 1) | (unsigned long long)b; ++nacc; ++nb;
        if (nacc >= 32u) {
            outw[wp++] = __builtin_bswap32((unsigned)(acc >> (nacc - 32u)));
            nacc -= 32u;
        }
    };

    const uint4* p = (const uint4*)fb;
    uint4 A = p[0], B = p[1];                // chunk 0 preload (16 symbols)
    const int NC = N_TOT / 16;
    for (int c = 0; c < NC; ++c) {
        unsigned sw[8];
        sw[0] = __builtin_amdgcn_readfirstlane(A.x);
        sw[1] = __builtin_amdgcn_readfirstlane(A.y);
        sw[2] = __builtin_amdgcn_readfirstlane(A.z);
        sw[3] = __builtin_amdgcn_readfirstlane(A.w);
        sw[4] = __builtin_amdgcn_readfirstlane(B.x);
        sw[5] = __builtin_amdgcn_readfirstlane(B.y);
        sw[6] = __builtin_amdgcn_readfirstlane(B.z);
        sw[7] = __builtin_amdgcn_readfirstlane(B.w);
        if (c + 1 < NC) { A = p[2 * c + 2]; B = p[2 * c + 3]; }  // prefetch next chunk
#pragma unroll
        for (int j = 0; j < 16; ++j) {
            unsigned val = (sw[j >> 1] >> ((j & 1) << 4)) & 0xFFFFu;
            unsigned f = val & 0xFFFu;
            unsigned bitv = val >> 15;
            // interval narrowing: split = low + ((high-low+1)*f) >> 12
            unsigned r = high - low;                       // rng - 1
            unsigned plo = r * f;
            unsigned phi = __umulhi(r, f);
            unsigned long long prod = (((unsigned long long)phi << 32) | plo) + f;
            unsigned split = low + (unsigned)(prod >> 12);
            high = bitv ? high : (split - 1u);
            low  = bitv ? split : low;
            // batched common-MSB emission: k bits + pending complements, one append
            unsigned x = low ^ high;                       // never 0 (rng > 2^18)
            unsigned k = (unsigned)__builtin_clz(x);       // 0..31
            if (k) {
                unsigned b0 = low >> 31;
                unsigned Lb = k + pending;
                if (Lb <= 32u) {
                    // payload = b0 | pending x (~b0) | bits 1..k-1 of low (MSB-first)
                    unsigned long long t =
                        (((unsigned long long)low) >> (32u - k)) & ((1ull << (k - 1u)) - 1ull);
                    unsigned long long comp =
                        b0 ? 0ull : (((1ull << pending) - 1ull) << (k - 1u));
                    unsigned long long V = ((unsigned long long)b0 << (Lb - 1u)) | comp | t;
                    acc = (acc << Lb) | V; nacc += Lb; nb += Lb;
                    if (nacc >= 32u) {
                        outw[wp++] = __builtin_bswap32((unsigned)(acc >> (nacc - 32u)));
                        nacc -= 32u;
                    }
                } else {                                   // rare: long pending run
                    EMIT1(b0);
                    unsigned pd = pending;
                    while (pd) { EMIT1(1u - b0); --pd; }
                    for (unsigned i = 1; i < k; ++i) EMIT1((low >> (31u - i)) & 1u);
                }
                pending = 0;
                low <<= k;
                high = (high << k) | ((1u << k) - 1u);     // k <= 31
            }
            // batched E3 (straddle) steps, unconditional (m=0 is identity)
            unsigned nt1 = ~(low << 1);                    // LSB=1 -> nonzero
            unsigned t2g = (high << 1) | 1u;               // |1 guards t2==0 (proof: a<=31)
            unsigned a  = (unsigned)__builtin_clz(nt1);
            unsigned bq = (unsigned)__builtin_clz(t2g);
            unsigned m = a < bq ? a : bq;                  // 0..31
            pending += m;
            unsigned long long pm1 = (1ull << m) - 1ull;
            low  = (unsigned)((((unsigned long long)low)  << m) - (pm1 << 31));
            high = (unsigned)(((((unsigned long long)high) << m) - (pm1 << 31)) + pm1);
        }
    }
    // flush
    pending += 1u;
    unsigned fbit = (low >= 0x40000000u) ? 1u : 0u;
    EMIT1(fbit);
    while (pending) { EMIT1(1u - fbit); --pending; }
    if (nacc) outw[wp++] = __builtin_bswap32((unsigned)(acc << (32u - nacc)));
    hdr[0] = nb;
    hdr[1] = wp;
}

__global__ void k_out(const unsigned char* __restrict__ bytes,
                      const unsigned* __restrict__ hdr, int* __restrict__ out) {
    int i = blockIdx.x * blockDim.x + threadIdx.x;
    if (i > 262144) return;
    if (i == 262144) { out[i] = (int)hdr[0]; return; }
    unsigned nbytes = hdr[1] * 4u;
    out[i] = ((unsigned)i < nbytes) ? (int)bytes[i] : 0;
}

extern "C" void kernel_launch(void* const* d_in, const int* in_sizes, int n_in,
                              void* d_out, int out_size, void* d_ws, size_t ws_size,
                              hipStream_t stream) {
    (void)in_sizes; (void)n_in; (void)out_size; (void)ws_size;
    const float* sym = (const float*)d_in[0];
    int* out = (int*)d_out;
    char* ws = (char*)d_ws;
    unsigned*       hdr   = (unsigned*)(ws);
    unsigned*       outw  = (unsigned*)(ws + 4096);
    unsigned*       histG = (unsigned*)(ws + 266240);
    unsigned*       offsG = (unsigned*)(ws + 790528);
    unsigned short* keys  = (unsigned short*)(ws + 1314816);
    unsigned short* fb    = (unsigned short*)(ws + 3411968);

    k_keys<<<N_TOT / 256, 256, 0, stream>>>(sym, keys);
    k_hist<<<N_BLKS, 256, 0, stream>>>(keys, histG);
    k_scan<<<1, 512, 0, stream>>>(histG, offsG);
    k_freq<<<N_BLKS, 64, 0, stream>>>(keys, offsG, fb);
    k_encode<<<1, 64, 0, stream>>>(fb, outw, hdr);
    k_out<<<1025, 256, 0, stream>>>((const unsigned char*)outw, hdr, out);
}